// Round 1
// baseline (1109.511 us; speedup 1.0000x reference)
//
#include <hip/hip_runtime.h>

#define WIDTH   1024
#define HALF_W  512
#define DEPTH   8
#define BDEPTH  10
#define BATCH   65536
#define ROWS    32          // batch rows per block (2 row-groups of 16)

typedef _Float16 v8h __attribute__((ext_vector_type(8)));   // MFMA A/B frag (4 VGPR)
typedef _Float16 v4h __attribute__((ext_vector_type(4)));   // packed 4 x fp16 (8 B)
typedef float    v4f __attribute__((ext_vector_type(4)));   // MFMA C/D frag

static __device__ __forceinline__ unsigned short f2h(float x) {
    _Float16 h = (_Float16)x;                 // RNE, rel err <= 2^-11
    return __builtin_bit_cast(unsigned short, h);
}

// ---------------------------------------------------------------------------
// LDS layout: 32 slices x 32 rows x 32 fp16, slice stride 2048 B (no pad).
// Swizzle: byte ^= (((r>>1) ^ slice) & 7) << 4.
//   Bijective: the XOR touches bits [6:4] only; slice = bits>=11 and
//   r>>1 = bits [10:7] are invariant under it.
//   Conflict-free per 8-lane octet for all three access shapes used here:
//     A-read  b128: lanes (lw,q) -> slot ((4*lw+q)^ (lw>>1)) & 7   : distinct
//     T-write b64 : lanes vary slice=nt*16+lw -> slot ^= lw&7      : distinct
//     init  b128  : lanes vary slice=g        -> slot ^= g&7       : distinct
// ---------------------------------------------------------------------------
static __device__ __forceinline__ int xoff(int slice, int r, int k) {
    int b = (slice << 11) + (r << 6) + (k << 1);
    return b ^ ((((r >> 1) ^ slice) & 7) << 4);
}

// ---------------------------------------------------------------------------
// Setup: compose 5 butterfly steps into 32x32 matrices, write in B-frag order.
// (unchanged from verified kernel)
// ---------------------------------------------------------------------------
__global__ void gen_mats(const float* __restrict__ bp, unsigned short* __restrict__ mats)
{
    const int bid = blockIdx.x;
    const int grp = bid & 31;
    const int ph  = (bid >> 5) & 1;
    const int L   = bid >> 6;
    const int tid = threadIdx.x;

    __shared__ float M[2][32][32];

    for (int i = tid; i < 1024; i += 64)
        M[0][i >> 5][i & 31] = ((i >> 5) == (i & 31)) ? 1.0f : 0.0f;
    __syncthreads();

    int buf = 0;
    for (int s = 0; s < 5; ++s) {
        const int t = ph * 5 + s;
        const int stride = 1 << (4 - s);
        for (int idx = tid; idx < 512; idx += 64) {
            const int a  = idx >> 5;
            const int c  = idx & 31;
            const int lo = ((a & ~(stride - 1)) << 1) | (a & (stride - 1));
            const int hi = lo | stride;
            const int p_low = (ph == 0) ? ((lo << 5) | grp) : ((grp << 5) | lo);
            const int j = (((p_low << t) | (p_low >> (10 - t))) & 1023) & 511;
            const float theta = bp[L * (HALF_W * BDEPTH) + j * BDEPTH + t];
            float sn, cs;
            sincosf(theta, &sn, &cs);
            const float xl = M[buf][lo][c];
            const float xh = M[buf][hi][c];
            M[1 - buf][lo][c] =  cs * xl + sn * xh;
            M[1 - buf][hi][c] = -sn * xl + cs * xh;
        }
        buf = 1 - buf;
        __syncthreads();
    }

    unsigned short* out = mats + (size_t)bid * 1024;
    for (int i = tid; i < 1024; i += 64) {
        const int nt   = i >> 9;
        const int lane = (i >> 3) & 63;
        const int jj   = i & 7;
        const int n = nt * 16 + (lane & 15);
        const int k = (lane >> 4) * 8 + jj;
        out[i] = f2h(M[buf][n][k]);
    }
}

// ---------------------------------------------------------------------------
// Fuse activation constants: {slope/scale, bias/scale, scale, 0} per (L, p).
// Removes the per-element rcp and one mul from the hot loop.
// ---------------------------------------------------------------------------
__global__ void fuse_act(const float* __restrict__ bias,
                         const float* __restrict__ slope,
                         const float* __restrict__ scale,
                         float4* __restrict__ actT)
{
    const int i = blockIdx.x * 256 + threadIdx.x;
    if (i < (DEPTH - 1) * WIDTH) {
        const float b = bias[i], s = slope[i], c = scale[i];
        const float r = 1.0f / c;
        actT[i] = make_float4(s * r, b * r, c, 0.0f);
    }
}

// ---------------------------------------------------------------------------
// Main: 32 rows per block, 512 threads (8 waves = 2 row-groups x 4 octets).
// Single 64 KB LDS buffer; phases transpose in place:
//   [stage 8 A-frags -> regs][BAR][MFMA + (act) + transposed write][BAR]
// 2 blocks/CU -> 16 waves/CU. Each B-frag is shared by the 2 row-group
// waves via L1, halving distinct L2 B-matrix traffic vs 16-row blocks.
// ---------------------------------------------------------------------------
__global__ void __launch_bounds__(512, 4) butterfly_net(
    const float* __restrict__ X,
    const unsigned short* __restrict__ mats,
    const float4* __restrict__ actT,
    float* __restrict__ out)
{
    __shared__ unsigned char Xb[32 * 2048];   // 64 KB exactly

    const int tid  = threadIdx.x;
    const int lane = tid & 63;
    const int wv   = tid >> 6;        // wave 0..7
    const int oct  = wv & 3;          // slice octet
    const int rg   = wv >> 2;         // row group 0/1
    const int lw   = lane & 15;
    const int q    = lane >> 4;
    const int row0 = blockIdx.x * ROWS;
    const int rbase = rg * 16;

    // ---- initial staging: fp32 global -> fp16 LDS, layout (g, r, h)
    {
        const int g = tid & 31;
        const int m = tid >> 5;                   // 0..15
        #pragma unroll
        for (int it = 0; it < 8; ++it) {
            const int cmb = it * 16 + m;          // 0..127
            const int r   = cmb >> 2;             // 0..31
            const int h0  = (cmb & 3) * 8;        // 0,8,16,24
            const float* src = X + (size_t)(row0 + r) * WIDTH + (size_t)h0 * 32 + g;
            v8h pk;
            #pragma unroll
            for (int j = 0; j < 8; ++j)
                pk[j] = (_Float16)src[j * 32];    // column 32*(h0+j)+g
            *(v8h*)(Xb + xoff(g, r, h0)) = pk;
        }
    }
    __syncthreads();

    for (int L = 0; L < DEPTH; ++L) {
        const bool last = (L == DEPTH - 1);

        // ================= phase 1: mix h (slices = g) =================
        {
            const unsigned short* m1 = mats + (size_t)(L * 2 + 0) * 32 * 1024;
            v8h aF[8];
            #pragma unroll
            for (int i = 0; i < 8; ++i)
                aF[i] = *(const v8h*)(Xb + xoff(oct * 8 + i, rbase + lw, q * 8));
            __syncthreads();                      // all reads landed before writes
            #pragma unroll
            for (int s = 0; s < 2; ++s) {
                const int gbase = oct * 8 + s * 4;
                #pragma unroll
                for (int nt = 0; nt < 2; ++nt) {
                    v4f C[4];
                    #pragma unroll
                    for (int gi = 0; gi < 4; ++gi) {
                        const v8h B = *(const v8h*)&m1[(size_t)(gbase + gi) * 1024
                                                       + nt * 512 + lane * 8];
                        C[gi] = __builtin_amdgcn_mfma_f32_16x16x32_f16(
                            aF[s * 4 + gi], B, (v4f){0.f, 0.f, 0.f, 0.f}, 0, 0, 0);
                    }
                    const int hout = nt * 16 + lw;
                    #pragma unroll
                    for (int r = 0; r < 4; ++r) {
                        v4h pk = { (_Float16)C[0][r], (_Float16)C[1][r],
                                   (_Float16)C[2][r], (_Float16)C[3][r] };
                        *(v4h*)(Xb + xoff(hout, rbase + q * 4 + r, gbase)) = pk;
                    }
                }
            }
            __syncthreads();
        }

        // ================= phase 2: mix g (slices = h), + activation ====
        {
            const unsigned short* m2 = mats + (size_t)(L * 2 + 1) * 32 * 1024;
            v8h aF[8];
            #pragma unroll
            for (int i = 0; i < 8; ++i)
                aF[i] = *(const v8h*)(Xb + xoff(oct * 8 + i, rbase + lw, q * 8));
            __syncthreads();
            #pragma unroll
            for (int s = 0; s < 2; ++s) {
                const int hbase = oct * 8 + s * 4;
                #pragma unroll
                for (int nt = 0; nt < 2; ++nt) {
                    v4f C[4];
                    #pragma unroll
                    for (int hi = 0; hi < 4; ++hi) {
                        const v8h B = *(const v8h*)&m2[(size_t)(hbase + hi) * 1024
                                                       + nt * 512 + lane * 8];
                        C[hi] = __builtin_amdgcn_mfma_f32_16x16x32_f16(
                            aF[s * 4 + hi], B, (v4f){0.f, 0.f, 0.f, 0.f}, 0, 0, 0);
                    }
                    const int gout = nt * 16 + lw;
                    if (!last) {
                        float4 ac[4];
                        #pragma unroll
                        for (int hi = 0; hi < 4; ++hi)
                            ac[hi] = actT[(size_t)L * WIDTH + (hbase + hi) * 32 + gout];
                        #pragma unroll
                        for (int r = 0; r < 4; ++r) {
                            v4h pk;
                            #pragma unroll
                            for (int hi = 0; hi < 4; ++hi) {
                                float u = fmaf(C[hi][r], ac[hi].x, -ac[hi].y);
                                u = fminf(1.0f, fmaxf(-1.0f, u));   // -> v_med3
                                const float u2 = u * u;
                                const float p5 = fmaf(u2, 0.375f, -1.25f);
                                const float p3 = fmaf(u2, p5, 1.875f);
                                pk[hi] = (_Float16)(u * p3 * ac[hi].z);
                            }
                            *(v4h*)(Xb + xoff(gout, rbase + q * 4 + r, hbase)) = pk;
                        }
                    } else {
                        #pragma unroll
                        for (int hi = 0; hi < 4; ++hi) {
                            #pragma unroll
                            for (int r = 0; r < 4; ++r)
                                out[(size_t)(row0 + rbase + q * 4 + r) * WIDTH
                                    + (hbase + hi) * 32 + gout] = C[hi][r];
                        }
                    }
                }
            }
            if (!last) __syncthreads();
        }
    }
}

extern "C" void kernel_launch(void* const* d_in, const int* in_sizes, int n_in,
                              void* d_out, int out_size, void* d_ws, size_t ws_size,
                              hipStream_t stream)
{
    const float* X     = (const float*)d_in[0];
    const float* bp    = (const float*)d_in[1];
    const float* bias  = (const float*)d_in[2];
    const float* slope = (const float*)d_in[3];
    const float* scale = (const float*)d_in[4];
    unsigned short* mats = (unsigned short*)d_ws;                    // 1 MB
    float4* actT = (float4*)((char*)d_ws + 512 * 1024 * 2);          // 112 KB

    hipLaunchKernelGGL(gen_mats, dim3(512), dim3(64), 0, stream, bp, mats);
    hipLaunchKernelGGL(fuse_act, dim3(((DEPTH - 1) * WIDTH + 255) / 256), dim3(256),
                       0, stream, bias, slope, scale, actT);
    hipLaunchKernelGGL(butterfly_net, dim3(BATCH / ROWS), dim3(512), 0, stream,
                       X, mats, actT, (float*)d_out);
}

// Round 2
// 810.668 us; speedup vs baseline: 1.3686x; 1.3686x over previous
//
#include <hip/hip_runtime.h>

#define WIDTH   1024
#define HALF_W  512
#define DEPTH   8
#define BDEPTH  10
#define BATCH   65536
#define ROWS    32          // batch rows per block (2 row-groups of 16)

typedef _Float16 v8h __attribute__((ext_vector_type(8)));   // MFMA A/B frag (4 VGPR)
typedef _Float16 v4h __attribute__((ext_vector_type(4)));   // packed 4 x fp16 (8 B)
typedef float    v4f __attribute__((ext_vector_type(4)));   // MFMA C/D frag

static __device__ __forceinline__ unsigned short f2h(float x) {
    _Float16 h = (_Float16)x;                 // RNE, rel err <= 2^-11
    return __builtin_bit_cast(unsigned short, h);
}

// ---------------------------------------------------------------------------
// LDS layout: 32 slices x 32 rows x 32 fp16, slice stride 2048 B (no pad).
// Swizzle: byte ^= (((r>>1) ^ slice) & 7) << 4.
//   Bijective: the XOR touches bits [6:4] only; slice = bits>=11 and
//   r>>1 = bits [10:7] are invariant under it.
//   Verified at quarter-wave granularity (16 lanes/cycle-group):
//     A-read  b128: 2 lanes per 16B slot -> conflict-free
//     T-write b64 : 2 lanes per 8B slot  -> 2-way (free per m136)
//     init  b128  : lanes vary slice     -> distinct slots
// ---------------------------------------------------------------------------
static __device__ __forceinline__ int xoff(int slice, int r, int k) {
    int b = (slice << 11) + (r << 6) + (k << 1);
    return b ^ ((((r >> 1) ^ slice) & 7) << 4);
}

// ---------------------------------------------------------------------------
// Setup: compose 5 butterfly steps into 32x32 matrices, write in B-frag order.
// ---------------------------------------------------------------------------
__global__ void gen_mats(const float* __restrict__ bp, unsigned short* __restrict__ mats)
{
    const int bid = blockIdx.x;
    const int grp = bid & 31;
    const int ph  = (bid >> 5) & 1;
    const int L   = bid >> 6;
    const int tid = threadIdx.x;

    __shared__ float M[2][32][32];

    for (int i = tid; i < 1024; i += 64)
        M[0][i >> 5][i & 31] = ((i >> 5) == (i & 31)) ? 1.0f : 0.0f;
    __syncthreads();

    int buf = 0;
    for (int s = 0; s < 5; ++s) {
        const int t = ph * 5 + s;
        const int stride = 1 << (4 - s);
        for (int idx = tid; idx < 512; idx += 64) {
            const int a  = idx >> 5;
            const int c  = idx & 31;
            const int lo = ((a & ~(stride - 1)) << 1) | (a & (stride - 1));
            const int hi = lo | stride;
            const int p_low = (ph == 0) ? ((lo << 5) | grp) : ((grp << 5) | lo);
            const int j = (((p_low << t) | (p_low >> (10 - t))) & 1023) & 511;
            const float theta = bp[L * (HALF_W * BDEPTH) + j * BDEPTH + t];
            float sn, cs;
            sincosf(theta, &sn, &cs);
            const float xl = M[buf][lo][c];
            const float xh = M[buf][hi][c];
            M[1 - buf][lo][c] =  cs * xl + sn * xh;
            M[1 - buf][hi][c] = -sn * xl + cs * xh;
        }
        buf = 1 - buf;
        __syncthreads();
    }

    unsigned short* out = mats + (size_t)bid * 1024;
    for (int i = tid; i < 1024; i += 64) {
        const int nt   = i >> 9;
        const int lane = (i >> 3) & 63;
        const int jj   = i & 7;
        const int n = nt * 16 + (lane & 15);
        const int k = (lane >> 4) * 8 + jj;
        out[i] = f2h(M[buf][n][k]);
    }
}

// ---------------------------------------------------------------------------
// Fuse activation constants: {slope/scale, bias/scale, scale, 0} per (L, p).
// ---------------------------------------------------------------------------
__global__ void fuse_act(const float* __restrict__ bias,
                         const float* __restrict__ slope,
                         const float* __restrict__ scale,
                         float4* __restrict__ actT)
{
    const int i = blockIdx.x * 256 + threadIdx.x;
    if (i < (DEPTH - 1) * WIDTH) {
        const float b = bias[i], s = slope[i], c = scale[i];
        const float r = 1.0f / c;
        actT[i] = make_float4(s * r, b * r, c, 0.0f);
    }
}

// ---------------------------------------------------------------------------
// Main: 32 rows per block, 512 threads (8 waves = 2 row-groups x 4 octets).
// Single 64 KB LDS buffer; phases transpose in place:
//   [stage 8 A-frags -> regs][BAR][MFMA + (act) + transposed write][BAR]
// __launch_bounds__(512, 2): CUDA semantics = min 2 BLOCKS/CU -> 16 waves/CU
// -> 128-VGPR cap. (512, 4) capped at 64 VGPRs and spilled ~1.4 GB of
// scratch traffic to HBM (R1 post-mortem: FETCH 1.22 GB, VGPR_Count 64).
// ---------------------------------------------------------------------------
__global__ void __launch_bounds__(512, 2) butterfly_net(
    const float* __restrict__ X,
    const unsigned short* __restrict__ mats,
    const float4* __restrict__ actT,
    float* __restrict__ out)
{
    __shared__ unsigned char Xb[32 * 2048];   // 64 KB exactly -> 2 blocks/CU

    const int tid  = threadIdx.x;
    const int lane = tid & 63;
    const int wv   = tid >> 6;        // wave 0..7
    const int oct  = wv & 3;          // slice octet
    const int rg   = wv >> 2;         // row group 0/1
    const int lw   = lane & 15;
    const int q    = lane >> 4;
    const int row0 = blockIdx.x * ROWS;
    const int rbase = rg * 16;

    // ---- initial staging: fp32 global -> fp16 LDS, layout (g, r, h)
    {
        const int g = tid & 31;
        const int m = tid >> 5;                   // 0..15
        #pragma unroll
        for (int it = 0; it < 8; ++it) {
            const int cmb = it * 16 + m;          // 0..127
            const int r   = cmb >> 2;             // 0..31
            const int h0  = (cmb & 3) * 8;        // 0,8,16,24
            const float* src = X + (size_t)(row0 + r) * WIDTH + (size_t)h0 * 32 + g;
            v8h pk;
            #pragma unroll
            for (int j = 0; j < 8; ++j)
                pk[j] = (_Float16)src[j * 32];    // column 32*(h0+j)+g
            *(v8h*)(Xb + xoff(g, r, h0)) = pk;
        }
    }
    __syncthreads();

    for (int L = 0; L < DEPTH; ++L) {
        const bool last = (L == DEPTH - 1);

        // ================= phase 1: mix h (slices = g) =================
        {
            const unsigned short* m1 = mats + (size_t)(L * 2 + 0) * 32 * 1024;
            v8h aF[8];
            #pragma unroll
            for (int i = 0; i < 8; ++i)
                aF[i] = *(const v8h*)(Xb + xoff(oct * 8 + i, rbase + lw, q * 8));
            __syncthreads();                      // all reads landed before writes
            #pragma unroll
            for (int s = 0; s < 2; ++s) {
                const int gbase = oct * 8 + s * 4;
                #pragma unroll
                for (int nt = 0; nt < 2; ++nt) {
                    v4f C[4];
                    #pragma unroll
                    for (int gi = 0; gi < 4; ++gi) {
                        const v8h B = *(const v8h*)&m1[(size_t)(gbase + gi) * 1024
                                                       + nt * 512 + lane * 8];
                        C[gi] = __builtin_amdgcn_mfma_f32_16x16x32_f16(
                            aF[s * 4 + gi], B, (v4f){0.f, 0.f, 0.f, 0.f}, 0, 0, 0);
                    }
                    const int hout = nt * 16 + lw;
                    #pragma unroll
                    for (int r = 0; r < 4; ++r) {
                        v4h pk = { (_Float16)C[0][r], (_Float16)C[1][r],
                                   (_Float16)C[2][r], (_Float16)C[3][r] };
                        *(v4h*)(Xb + xoff(hout, rbase + q * 4 + r, gbase)) = pk;
                    }
                }
            }
            __syncthreads();
        }

        // ================= phase 2: mix g (slices = h), + activation ====
        {
            const unsigned short* m2 = mats + (size_t)(L * 2 + 1) * 32 * 1024;
            v8h aF[8];
            #pragma unroll
            for (int i = 0; i < 8; ++i)
                aF[i] = *(const v8h*)(Xb + xoff(oct * 8 + i, rbase + lw, q * 8));
            __syncthreads();
            #pragma unroll
            for (int s = 0; s < 2; ++s) {
                const int hbase = oct * 8 + s * 4;
                #pragma unroll
                for (int nt = 0; nt < 2; ++nt) {
                    v4f C[4];
                    #pragma unroll
                    for (int hi = 0; hi < 4; ++hi) {
                        const v8h B = *(const v8h*)&m2[(size_t)(hbase + hi) * 1024
                                                       + nt * 512 + lane * 8];
                        C[hi] = __builtin_amdgcn_mfma_f32_16x16x32_f16(
                            aF[s * 4 + hi], B, (v4f){0.f, 0.f, 0.f, 0.f}, 0, 0, 0);
                    }
                    const int gout = nt * 16 + lw;
                    if (!last) {
                        float4 ac[4];
                        #pragma unroll
                        for (int hi = 0; hi < 4; ++hi)
                            ac[hi] = actT[(size_t)L * WIDTH + (hbase + hi) * 32 + gout];
                        #pragma unroll
                        for (int r = 0; r < 4; ++r) {
                            v4h pk;
                            #pragma unroll
                            for (int hi = 0; hi < 4; ++hi) {
                                float u = fmaf(C[hi][r], ac[hi].x, -ac[hi].y);
                                u = fminf(1.0f, fmaxf(-1.0f, u));   // -> v_med3
                                const float u2 = u * u;
                                const float p5 = fmaf(u2, 0.375f, -1.25f);
                                const float p3 = fmaf(u2, p5, 1.875f);
                                pk[hi] = (_Float16)(u * p3 * ac[hi].z);
                            }
                            *(v4h*)(Xb + xoff(gout, rbase + q * 4 + r, hbase)) = pk;
                        }
                    } else {
                        #pragma unroll
                        for (int hi = 0; hi < 4; ++hi) {
                            #pragma unroll
                            for (int r = 0; r < 4; ++r)
                                out[(size_t)(row0 + rbase + q * 4 + r) * WIDTH
                                    + (hbase + hi) * 32 + gout] = C[hi][r];
                        }
                    }
                }
            }
            if (!last) __syncthreads();
        }
    }
}

extern "C" void kernel_launch(void* const* d_in, const int* in_sizes, int n_in,
                              void* d_out, int out_size, void* d_ws, size_t ws_size,
                              hipStream_t stream)
{
    const float* X     = (const float*)d_in[0];
    const float* bp    = (const float*)d_in[1];
    const float* bias  = (const float*)d_in[2];
    const float* slope = (const float*)d_in[3];
    const float* scale = (const float*)d_in[4];
    unsigned short* mats = (unsigned short*)d_ws;                    // 1 MB
    float4* actT = (float4*)((char*)d_ws + 512 * 1024 * 2);          // 112 KB

    hipLaunchKernelGGL(gen_mats, dim3(512), dim3(64), 0, stream, bp, mats);
    hipLaunchKernelGGL(fuse_act, dim3(((DEPTH - 1) * WIDTH + 255) / 256), dim3(256),
                       0, stream, bias, slope, scale, actT);
    hipLaunchKernelGGL(butterfly_net, dim3(BATCH / ROWS), dim3(512), 0, stream,
                       X, mats, actT, (float*)d_out);
}